// Round 18
// baseline (257.704 us; speedup 1.0000x reference)
//
#include <hip/hip_runtime.h>
#include <hip/hip_bf16.h>

// ---------------- problem constants ----------------
#define E_    8
#define TT    4096      // tokens = B*S
#define DD    512
#define HH    2048
#define CAP   1075      // round(2*4096*1.05/8)
#define MPAD  1152      // 9 * 128, padded rows per expert
#define MT    9         // 128-row M tiles per expert (gemm1)
#define MT2   18        // 64-row M tiles per expert (gemm2)

typedef __bf16 bf16_t;
typedef bf16_t bf16x4 __attribute__((ext_vector_type(4)));
typedef bf16_t bf16x8 __attribute__((ext_vector_type(8)));
typedef float  f32x4  __attribute__((ext_vector_type(4)));
typedef unsigned int u32;

__device__ __forceinline__ bf16_t tobf(float f) { return (bf16_t)f; }  // fptrunc, RNE

// tanh-form gelu: max |diff vs erf-gelu| ~3e-4 in h; through fc2's random-sign
// weights adds ~2e-4 to y (threshold 4.97e-2). exp overflow-safe via |u|+copysign.
__device__ __forceinline__ float gelu_f(float v) {
  const float u = v * (0.7978845608028654f + 0.035677408136300125f * v * v);
  const float a = __builtin_fabsf(u);
  const float ex = __expf(2.0f * a);
  float th = 1.0f - 2.0f / (ex + 1.0f);
  th = __builtin_copysignf(th, u);
  return 0.5f * v * (1.0f + th);
}

// counted vmcnt wait — immediate must be compile-time
template <int N> __device__ __forceinline__ void waitcnt_vm() {
  static_assert(N == 0 || N == 4 || N == 6, "unsupported vmcnt");
  if constexpr (N == 0) asm volatile("s_waitcnt vmcnt(0)" ::: "memory");
  else if constexpr (N == 4) asm volatile("s_waitcnt vmcnt(4)" ::: "memory");
  else if constexpr (N == 6) asm volatile("s_waitcnt vmcnt(6)" ::: "memory");
}
__device__ __forceinline__ void block_barrier() {
  asm volatile("" ::: "memory");      // compiler fence: no LDS access motion across
  __builtin_amdgcn_s_barrier();
  asm volatile("" ::: "memory");
}

// ---------------- workspace layout (bytes) ----------------
// hdr: imp[8] f32 @0, kept[8] i32 @64. etok adjacent so ONE memset covers
// hdr+etok (ewt needs no zeroing: epilogue guards m < kept[e]).
#define OFF_ETOK  256u                                 // etok[E][MPAD] i32
#define OFF_EWT   (OFF_ETOK + 8u*1152u*4u)             // ewt[E][MPAD] f32 (r27)
#define OFF_TOPI  (OFF_EWT + 8u*1152u*4u)
#define OFF_TOPG  (OFF_TOPI + 4096u*2u*4u)
#define OFF_SLOT  (OFF_TOPG + 4096u*2u*4u)             // slot_map[2*T] i32 (unused r27)
#define OFF_XB    (OFF_SLOT + 4096u*2u*4u)             // 16B aligned
#define XB_BYTES  (4096u*512u*2u)                      // 4,194,304
#define OFF_W1T   (OFF_XB + XB_BYTES)
#define W1T_BYTES (8u*512u*2048u*2u)                   // 16,777,216
#define OFF_W2T   (OFF_W1T + W1T_BYTES)
#define W2T_BYTES (8u*2048u*512u*2u)                   // 16,777,216
#define OFF_H     (OFF_W2T + W2T_BYTES)
#define H_BYTES   (8u*1152u*2048u*2u)                  // 37,748,736
// total ~75.7 MB
//
// SESSION LESSONS (r0-r28, MI355X):
//  - split-K fp32 atomics (4x traffic): -37% (r2). [1:1 atomics untested]
//  - LDS XOR swizzle on global-side of global_load_lds: conflicts 7.1M -> 0.
//  - C^T (swapped MFMA operands): packed 8B epilogue stores, +6%.
//  - blockIdx.x=expert XCD affinity: FETCH 46->21 MB.
//  - cooperative fusion via grid.sync: 3x REGRESSION (r6/r7/r10).
//  - r11: gather folded into gemm1 staging. r12 dbuf-drain0: NEUTRAL.
//  - r14 geometry: +7%. r18 counted-vmcnt dbuf: +5% (gemm1 41.2us, BEST 212.5).
//  - r19 MFMA 32x32x16: REFUTED LDS-port theory (MfmaUtil unchanged).
//    Six gemm1 variants all 41-46us/~15% MfmaUtil => small-shape plateau.
//  - r24: prep merge (transpose+router): NEUTRAL (213.9). Counters: harness
//    poison-fill = 2 x 40.9us (256 MiB @ 82% peak) INSIDE the measured
//    window => ~38% of dur_us is uncontrollable; controllable ~130us.
//  - r27: fuse combine into gemm2 epilogue — slot (e,m) maps to token
//    etok[e][m], weight ewt[e][m]; atomicAdd f32 to zeroed out
//    (<=2 contenders/element). Deletes combine kernel + Ybuf round-trip.
//  - r28: r27 resubmitted unchanged (acquisition timeout, no data).

// ---------------- prep: weight transpose+cast (blocks 0..4095) --------------
// ---------------- + router (blocks 4096..5119) -------------------------------
__global__ __launch_bounds__(256) void prep_kernel(
    const float* __restrict__ fc1, bf16_t* __restrict__ w1t,
    const float* __restrict__ fc2, bf16_t* __restrict__ w2t,
    const float* __restrict__ x, const float* __restrict__ gw,
    float* __restrict__ imp, int* __restrict__ top_i, float* __restrict__ top_g,
    bf16_t* __restrict__ xb) {
  __shared__ float tile[64][65];
  __shared__ float simp[4][E_];
  const int bid = blockIdx.x;
  const int tid = threadIdx.x;

  if (bid < 4096) {                     // ---- transpose part ----
    const int z = bid >> 8;             // 0..15
    const int rem = bid & 255;
    const bool first = (z < 8);
    const int e = first ? z : z - 8;
    const int R = first ? DD : HH;
    const int C = first ? HH : DD;
    const int ct = first ? (rem & 31) : (rem & 7);    // C/64 tiles
    const int rt = first ? (rem >> 5) : (rem >> 3);   // R/64 tiles
    const float* ip = (first ? fc1 : fc2) + (size_t)e * DD * HH;
    bf16_t* op = (first ? w1t : w2t) + (size_t)e * DD * HH;
    const int r0 = rt * 64, c0 = ct * 64;
    const int rr = tid >> 4, c4 = (tid & 15) * 4;     // read: 16 rows/pass, float4
#pragma unroll
    for (int p = 0; p < 4; ++p) {
      const int r = p * 16 + rr;
      const float4 v = *(const float4*)(ip + (size_t)(r0 + r) * C + c0 + c4);
      tile[r][c4 + 0] = v.x; tile[r][c4 + 1] = v.y;
      tile[r][c4 + 2] = v.z; tile[r][c4 + 3] = v.w;
    }
    __syncthreads();
    const int g = tid & 7, ob = tid >> 3;             // write: 8-row groups, 32 cols
#pragma unroll
    for (int p = 0; p < 2; ++p) {
      const int oc = p * 32 + ob;
      bf16_t o8[8];
#pragma unroll
      for (int k = 0; k < 8; ++k) o8[k] = tobf(tile[g * 8 + k][oc]);
      *(bf16x8*)(op + (size_t)(c0 + oc) * R + r0 + g * 8) = *(const bf16x8*)o8;  // 16B store
    }
    return;
  }

  // ---- router part ----
  const int rb = bid - 4096;            // 0..1023
  const int wid = tid >> 6, lane = tid & 63;
  const int t = rb * 4 + wid;

  float p[E_];
#pragma unroll
  for (int e = 0; e < E_; ++e) p[e] = 0.f;
  const float* xr = x + (size_t)t * DD;
  bf16_t* xo = xb + (size_t)t * DD;
#pragma unroll
  for (int it = 0; it < 2; ++it) {
    const int d = it * 256 + lane * 4;
    const float4 xv = *(const float4*)(xr + d);
    bf16_t o4[4] = {tobf(xv.x), tobf(xv.y), tobf(xv.z), tobf(xv.w)};
    *(bf16x4*)(xo + d) = *(const bf16x4*)o4;      // fused bf16 cast (feeds gemm1 A-gather)
#pragma unroll
    for (int e = 0; e < E_; ++e) {
      const float4 gv = *(const float4*)(gw + e * DD + d);
      p[e] += xv.x * gv.x + xv.y * gv.y + xv.z * gv.z + xv.w * gv.w;
    }
  }
#pragma unroll
  for (int off = 32; off > 0; off >>= 1) {
#pragma unroll
    for (int e = 0; e < E_; ++e) p[e] += __shfl_down(p[e], off);
  }

  if (lane == 0) {
    float mx = p[0];
#pragma unroll
    for (int e = 1; e < E_; ++e) mx = fmaxf(mx, p[e]);
    float g[E_]; float s = 0.f;
#pragma unroll
    for (int e = 0; e < E_; ++e) { g[e] = expf(p[e] - mx); s += g[e]; }
    const float inv = 1.f / s;
#pragma unroll
    for (int e = 0; e < E_; ++e) { g[e] *= inv; simp[wid][e] = g[e]; }
    // top-2, ties -> lowest index (matches jax.lax.top_k)
    int i0 = 0;
#pragma unroll
    for (int e = 1; e < E_; ++e) if (g[e] > g[i0]) i0 = e;
    int i1 = (i0 == 0) ? 1 : 0;
#pragma unroll
    for (int e = 0; e < E_; ++e) if (e != i0 && g[e] > g[i1]) i1 = e;
    top_i[t * 2 + 0] = i0;  top_i[t * 2 + 1] = i1;
    top_g[t * 2 + 0] = g[i0]; top_g[t * 2 + 1] = g[i1];
  }
  __syncthreads();
  if (tid < E_) {
    const float s = simp[0][tid] + simp[1][tid] + simp[2][tid] + simp[3][tid];
    atomicAdd(&imp[tid], s);
  }
}

// ---------------- capacity: packed shfl scan + dispatch + ewt + scalars ------
__global__ __launch_bounds__(1024) void capacity_kernel(
    const int* __restrict__ top_i, const float* __restrict__ top_g,
    const float* __restrict__ imp, int* __restrict__ etok, float* __restrict__ ewt,
    int* __restrict__ kept, float* __restrict__ scal) {
  __shared__ u32 wt[16][4];
  const int tid = threadIdx.x, wave = tid >> 6, lane = tid & 63;

  int eidx[8];
#pragma unroll
  for (int q = 0; q < 8; ++q) {
    const int j = tid * 8 + q;          // slot-major: j = k*T + t
    const int k = j >> 12, t = j & (TT - 1);
    eidx[q] = top_i[t * 2 + k];
  }
  u32 pk[4] = {0u, 0u, 0u, 0u};
#pragma unroll
  for (int q = 0; q < 8; ++q) pk[eidx[q] >> 1] += 1u << ((eidx[q] & 1) * 16);

  u32 v[4] = {pk[0], pk[1], pk[2], pk[3]};   // inclusive wave scan
#pragma unroll
  for (int off = 1; off < 64; off <<= 1) {
#pragma unroll
    for (int p = 0; p < 4; ++p) {
      const u32 n = (u32)__shfl_up((int)v[p], off);
      if (lane >= off) v[p] += n;
    }
  }
  if (lane == 63) {
#pragma unroll
    for (int p = 0; p < 4; ++p) wt[wave][p] = v[p];
  }
  __syncthreads();
  u32 base[4] = {0u, 0u, 0u, 0u}, tot[4] = {0u, 0u, 0u, 0u};
#pragma unroll
  for (int w = 0; w < 16; ++w) {
#pragma unroll
    for (int p = 0; p < 4; ++p) {
      const u32 xv = wt[w][p];
      if (w < wave) base[p] += xv;
      tot[p] += xv;
    }
  }
  int run[E_];
#pragma unroll
  for (int p = 0; p < 4; ++p) {
    const u32 excl = base[p] + v[p] - pk[p];    // exclusive thread prefix
    run[2 * p]     = (int)(excl & 0xFFFFu);
    run[2 * p + 1] = (int)(excl >> 16);
  }
#pragma unroll
  for (int q = 0; q < 8; ++q) {
    const int e = eidx[q];
    const int pos = run[e]++;           // counts ALL earlier same-expert entries
    const int j = tid * 8 + q;
    if (pos < CAP) {
      const int k = j >> 12, t = j & (TT - 1);
      etok[e * MPAD + pos] = t;
      ewt[e * MPAD + pos] = top_g[t * 2 + k];
    }
  }
  if (tid == 0) {
    float tpe[E_];
#pragma unroll
    for (int p = 0; p < 4; ++p) {
      const int t0 = (int)(tot[p] & 0xFFFFu), t1 = (int)(tot[p] >> 16);
      const int k0 = t0 < CAP ? t0 : CAP, k1 = t1 < CAP ? t1 : CAP;
      kept[2 * p] = k0; kept[2 * p + 1] = k1;
      tpe[2 * p] = (float)k0; tpe[2 * p + 1] = (float)k1;
    }
    float ms = 0.f;
#pragma unroll
    for (int e = 0; e < E_; ++e) ms += tpe[e];
    ms *= (1.f / E_);
    float vt = 0.f;
#pragma unroll
    for (int e = 0; e < E_; ++e) { const float d = tpe[e] - ms; vt += d * d; }
    vt *= (1.f / E_);
    const float ll = vt / ((ms + 1e-6f) * (ms + 1e-6f));

    float iv[E_], mi = 0.f;
#pragma unroll
    for (int e = 0; e < E_; ++e) { iv[e] = imp[e]; mi += iv[e]; }
    mi *= (1.f / E_);
    float vi = 0.f;
#pragma unroll
    for (int e = 0; e < E_; ++e) { const float d = iv[e] - mi; vi += d * d; }
    vi *= (1.f / E_);
    const float il = vi / ((mi + 1e-6f) * (mi + 1e-6f));

    scal[0] = 0.5f * (il + ll);   // l_aux
    scal[1] = ll;                 // l_load
  }
}

// ---------------- TN GEMM core: counted-vmcnt dbuf pipeline (r18, proven) ----
// NW waves, tile MR x NC, BK=64 per step, DOUBLE-buffered LDS. Per step:
//   compute(buf s&1) -> s_barrier -> stage(s+2 -> buf s&1) ->
//   s_waitcnt vmcnt(L) (waits ONLY step s+1's loads) -> s_barrier.
// NEVER drains vmcnt to 0 in the loop (m218 mechanism).
// A: GATHER via per-lane etok row lookup on the global source of
// global_load_lds (LDS dest linear). B pre-transposed [col][K].
// acc[j][i] = mfma(bfr[j], af[i], acc) -> C^T tile: lane&15 -> m,
// quad*4+reg -> n -> packed epilogue. 16B-chunk XOR swizzle on the
// GLOBAL-side address; read side XORs with l15&7. Conflicts: 0 (proven).
template <int NW, int MR, int NC, int MI, int KLEN, int KSTR, bool GATHER>
__device__ __forceinline__ void gemm_core(
    const bf16_t* __restrict__ Abase, const int* __restrict__ rows,
    const bf16_t* __restrict__ B,
    bf16_t* As, bf16_t* Bs, f32x4 (&acc)[4][MI]) {
  constexpr int NWC = NC / 64;          // wave columns
  constexpr int AIW = MR / (8 * NW);    // A load-instrs per wave per step
  constexpr int BIW = NC / (8 * NW);    // B load-instrs per wave per step
  constexpr int L   = AIW + BIW;        // outstanding loads per staged step
  constexpr int NS  = KLEN / 64;        // K-steps
  constexpr int ABUF = MR * 64;         // elements per A buffer
  constexpr int BBUF = NC * 64;
  static_assert(NS >= 2, "need >=2 K-steps");
  const int tid = threadIdx.x;
  const int wave = tid >> 6, lane = tid & 63;
  const int r8 = lane >> 3;                       // row within 8-row group
  const int kswz = ((lane & 7) ^ r8) * 8;         // swizzled k-offset (elements)
  const bf16_t* ga[AIW];
#pragma unroll
  for (int p = 0; p < AIW; ++p) {
    const int r = (wave * AIW + p) * 8 + r8;
    const int trow = GATHER ? rows[r] : r;        // folded when !GATHER
    ga[p] = Abase + (size_t)trow * KSTR + kswz;
  }
  const bf16_t* gb = B + (size_t)(wave * BIW * 8 + r8) * KSTR + kswz;
  const int mw = (wave / NWC) * (MI * 16), nw = (wave % NWC) * 64;
  const int l15 = lane & 15, quad = lane >> 4;
  const int sw = l15 & 7;                         // read-side swizzle key

  auto stage = [&](int s) {
    const int k0 = s * 64;
    bf16_t* as = As + (s & 1) * ABUF;
    bf16_t* bs = Bs + (s & 1) * BBUF;
#pragma unroll
    for (int p = 0; p < AIW; ++p)
      __builtin_amdgcn_global_load_lds(
          (const __attribute__((address_space(1))) void*)(ga[p] + k0),
          (__attribute__((address_space(3))) void*)(as + ((wave * AIW + p) * 8) * 64),
          16, 0, 0);
#pragma unroll
    for (int p = 0; p < BIW; ++p)
      __builtin_amdgcn_global_load_lds(
          (const __attribute__((address_space(1))) void*)(gb + (size_t)p * 8 * KSTR + k0),
          (__attribute__((address_space(3))) void*)(bs + ((wave * BIW + p) * 8) * 64),
          16, 0, 0);
  };
  auto compute = [&](int s) {
    const bf16_t* as = As + (s & 1) * ABUF;
    const bf16_t* bs = Bs + (s & 1) * BBUF;
#pragma unroll
    for (int kh = 0; kh < 2; ++kh) {
      const int kc = ((kh * 4 + quad) ^ sw) << 3;           // swizzled chunk
      bf16x8 af[MI], bfr[4];
#pragma unroll
      for (int i = 0; i < MI; ++i)
        af[i] = *(const bf16x8*)(as + (mw + i * 16 + l15) * 64 + kc);
#pragma unroll
      for (int j = 0; j < 4; ++j)
        bfr[j] = *(const bf16x8*)(bs + (nw + j * 16 + l15) * 64 + kc);
#pragma unroll
      for (int j = 0; j < 4; ++j)
#pragma unroll
        for (int i = 0; i < MI; ++i)
          acc[j][i] = __builtin_amdgcn_mfma_f32_16x16x32_bf16(bfr[j], af[i], acc[j][i], 0, 0, 0);
    }
  };

  // prologue: two steps in flight
  stage(0);
  stage(1);
  waitcnt_vm<L>();          // own step-0 loads retired (step-1's L still out)
  block_barrier();          // everyone's step-0 loads landed

#pragma unroll
  for (int s = 0; s < NS; ++s) {
    compute(s);
    block_barrier();                    // all waves done READING buf (s&1)
    if (s + 2 < NS) {
      stage(s + 2);                     // refill buf (s&1); 2L outstanding
      waitcnt_vm<L>();                  // oldest L (= step s+1's) retired
      block_barrier();                  // buf ((s+1)&1) ready for all
    } else if (s + 1 < NS) {
      waitcnt_vm<0>();                  // tail: only step s+1's L outstanding
      block_barrier();
    }
  }
}

// ---------------- GEMM1: H = gelu(gather(x) @ W1 + b1), 128x128, 8 waves ----
// blockIdx.x = expert -> XCD (id%8). Early-exit tiles fully past kept[e].
// dbuf LDS 64KB -> 2 blocks/CU, 16 resident waves/CU. L=4 loads/wave/step.
__global__ __launch_bounds__(512, 4) void gemm1_kernel(
    const bf16_t* __restrict__ xb, const int* __restrict__ etok,
    const int* __restrict__ kept, const bf16_t* __restrict__ W1t,
    const float* __restrict__ b1, bf16_t* __restrict__ Hbuf) {
  const int e = blockIdx.x, tileN = blockIdx.y, tileM = blockIdx.z;
  if (tileM * 128 >= kept[e]) return;             // uniform early-exit
  __shared__ __align__(16) bf16_t As[2 * 128 * 64];   // 32 KB
  __shared__ __align__(16) bf16_t Bs[2 * 128 * 64];   // 32 KB
  const bf16_t* B = W1t + ((size_t)e * HH + tileN * 128) * DD;
  f32x4 acc[4][2];
  const f32x4 z = {0.f, 0.f, 0.f, 0.f};
#pragma unroll
  for (int j = 0; j < 4; ++j)
#pragma unroll
    for (int i = 0; i < 2; ++i) acc[j][i] = z;
  gemm_core<8, 128, 128, 2, DD, DD, true>(xb, etok + e * MPAD + tileM * 128, B, As, Bs, acc);

  const int tid = threadIdx.x, wave = tid >> 6, lane = tid & 63;
  const int mw = (wave >> 1) * 32, nw = (wave & 1) * 64;
  const int l15 = lane & 15, quad = lane >> 4;
#pragma unroll
  for (int j = 0; j < 4; ++j) {
    const int n0 = tileN * 128 + nw + j * 16 + quad * 4;   // 4 consecutive n
    const float4 b4 = *(const float4*)(b1 + e * HH + n0);
#pragma unroll
    for (int i = 0; i < 2; ++i) {
      const int m = tileM * 128 + mw + i * 16 + l15;
      bf16x4 h4;
      h4.x = tobf(gelu_f(acc[j][i][0] + b4.x));
      h4.y = tobf(gelu_f(acc[j][i][1] + b4.y));
      h4.z = tobf(gelu_f(acc[j][i][2] + b4.z));
      h4.w = tobf(gelu_f(acc[j][i][3] + b4.w));
      *(bf16x4*)(Hbuf + ((size_t)e * MPAD + m) * HH + n0) = h4;   // 8B store
    }
  }
}

// ---------------- GEMM2+combine (r27): out[t] += w * (H@W2 + b2) -------------
// Row m of expert e IS slot pos=m: t = etok[e][m], w = ewt[e][m].
// atomicAdd f32 into zeroed out; <=2 contenders per element (top-2 routing).
// Dropped-token rows (m >= kept[e]) skipped -> out stays 0 from memset.
__global__ __launch_bounds__(256, 4) void gemm2_kernel(
    const bf16_t* __restrict__ Hbuf, const bf16_t* __restrict__ W2t,
    const int* __restrict__ kept, const int* __restrict__ etok,
    const float* __restrict__ ewt, const float* __restrict__ b2,
    float* __restrict__ out) {
  const int e = blockIdx.x, tileN = blockIdx.y, tileM = blockIdx.z;
  const int nk = kept[e];
  if (tileM * 64 >= nk) return;                   // uniform early-exit
  __shared__ __align__(16) bf16_t As[2 * 64 * 64];    // 16 KB
  __shared__ __align__(16) bf16_t Bs[2 * 128 * 64];   // 32 KB
  const bf16_t* A = Hbuf + ((size_t)e * MPAD + tileM * 64) * HH;
  const bf16_t* B = W2t + ((size_t)e * DD + tileN * 128) * HH;
  f32x4 acc[4][2];
  const f32x4 z = {0.f, 0.f, 0.f, 0.f};
#pragma unroll
  for (int j = 0; j < 4; ++j)
#pragma unroll
    for (int i = 0; i < 2; ++i) acc[j][i] = z;
  gemm_core<4, 64, 128, 2, HH, HH, false>(A, nullptr, B, As, Bs, acc);

  const int tid = threadIdx.x, wave = tid >> 6, lane = tid & 63;
  const int mw = (wave >> 1) * 32, nw = (wave & 1) * 64;
  const int l15 = lane & 15, quad = lane >> 4;
  // per-thread row info (2 i-values)
  int   trow[2];
  float wgt[2];
#pragma unroll
  for (int i = 0; i < 2; ++i) {
    const int m = tileM * 64 + mw + i * 16 + l15;
    const bool live = (m < nk);
    trow[i] = live ? etok[e * MPAD + m] : -1;
    wgt[i]  = live ? ewt[e * MPAD + m] : 0.f;
  }
#pragma unroll
  for (int j = 0; j < 4; ++j) {
    const int n0 = tileN * 128 + nw + j * 16 + quad * 4;   // 4 consecutive n
    const float4 b4 = *(const float4*)(b2 + e * DD + n0);
#pragma unroll
    for (int i = 0; i < 2; ++i) {
      if (trow[i] >= 0) {
        float* op = out + (size_t)trow[i] * DD + n0;
        const float w = wgt[i];
        atomicAdd(op + 0, w * (acc[j][i][0] + b4.x));
        atomicAdd(op + 1, w * (acc[j][i][1] + b4.y));
        atomicAdd(op + 2, w * (acc[j][i][2] + b4.z));
        atomicAdd(op + 3, w * (acc[j][i][3] + b4.w));
      }
    }
  }
}

// ---------------- launch ----------------
extern "C" void kernel_launch(void* const* d_in, const int* in_sizes, int n_in,
                              void* d_out, int out_size, void* d_ws, size_t ws_size,
                              hipStream_t stream) {
  const float* x      = (const float*)d_in[0];
  const float* gate_w = (const float*)d_in[1];
  const float* fc1_w  = (const float*)d_in[2];
  const float* fc1_b  = (const float*)d_in[3];
  const float* fc2_w  = (const float*)d_in[4];
  const float* fc2_b  = (const float*)d_in[5];
  float* out = (float*)d_out;

  char* ws = (char*)d_ws;
  float*  imp   = (float*)(ws + 0);
  int*    kept  = (int*)(ws + 64);
  int*    etok  = (int*)(ws + OFF_ETOK);
  float*  ewt   = (float*)(ws + OFF_EWT);
  int*    top_i = (int*)(ws + OFF_TOPI);
  float*  top_g = (float*)(ws + OFF_TOPG);
  bf16_t* xb    = (bf16_t*)(ws + OFF_XB);
  bf16_t* W1t   = (bf16_t*)(ws + OFF_W1T);
  bf16_t* W2t   = (bf16_t*)(ws + OFF_W2T);
  bf16_t* Hbuf  = (bf16_t*)(ws + OFF_H);
  float*  scal  = out + (size_t)TT * DD;

  hipMemsetAsync(ws, 0, OFF_EWT, stream);            // imp base + etok (pads -> token 0)
  hipMemsetAsync(out, 0, (size_t)TT * DD * 4, stream);  // fused-combine accumulator base

  // transpose (4096 blocks) + router (1024 blocks) merged.
  prep_kernel<<<5120, 256, 0, stream>>>(fc1_w, W1t, fc2_w, W2t,
                                        x, gate_w, imp, top_i, top_g, xb);
  capacity_kernel<<<1, 1024, 0, stream>>>(top_i, top_g, imp, etok, ewt, kept, scal);

  // blockIdx.x = expert -> XCD affinity (id % 8 round-robin heuristic)
  gemm1_kernel<<<dim3(E_, HH / 128, MT), 512, 0, stream>>>(xb, etok, kept, W1t, fc1_b, Hbuf);
  gemm2_kernel<<<dim3(E_, DD / 128, MT2), 256, 0, stream>>>(Hbuf, W2t, kept, etok, ewt, fc2_b, out);
}

// Round 19
// 209.718 us; speedup vs baseline: 1.2288x; 1.2288x over previous
//
#include <hip/hip_runtime.h>
#include <hip/hip_bf16.h>

// ---------------- problem constants ----------------
#define E_    8
#define TT    4096      // tokens = B*S
#define DD    512
#define HH    2048
#define CAP   1075      // round(2*4096*1.05/8)
#define MPAD  1152      // 9 * 128, padded rows per expert
#define MT    9         // 128-row M tiles per expert (gemm1)
#define MT2   18        // 64-row M tiles per expert (gemm2)

typedef __bf16 bf16_t;
typedef bf16_t bf16x4 __attribute__((ext_vector_type(4)));
typedef bf16_t bf16x8 __attribute__((ext_vector_type(8)));
typedef float  f32x4  __attribute__((ext_vector_type(4)));
typedef unsigned int u32;

__device__ __forceinline__ bf16_t tobf(float f) { return (bf16_t)f; }  // fptrunc, RNE

// tanh-form gelu: max |diff vs erf-gelu| ~3e-4 in h; through fc2's random-sign
// weights adds ~2e-4 to y (threshold 4.97e-2). exp overflow-safe via |u|+copysign.
__device__ __forceinline__ float gelu_f(float v) {
  const float u = v * (0.7978845608028654f + 0.035677408136300125f * v * v);
  const float a = __builtin_fabsf(u);
  const float ex = __expf(2.0f * a);
  float th = 1.0f - 2.0f / (ex + 1.0f);
  th = __builtin_copysignf(th, u);
  return 0.5f * v * (1.0f + th);
}

// counted vmcnt wait — immediate must be compile-time
template <int N> __device__ __forceinline__ void waitcnt_vm() {
  static_assert(N == 0 || N == 4 || N == 6, "unsupported vmcnt");
  if constexpr (N == 0) asm volatile("s_waitcnt vmcnt(0)" ::: "memory");
  else if constexpr (N == 4) asm volatile("s_waitcnt vmcnt(4)" ::: "memory");
  else if constexpr (N == 6) asm volatile("s_waitcnt vmcnt(6)" ::: "memory");
}
__device__ __forceinline__ void block_barrier() {
  asm volatile("" ::: "memory");      // compiler fence: no LDS access motion across
  __builtin_amdgcn_s_barrier();
  asm volatile("" ::: "memory");
}

// ---------------- workspace layout (bytes) ----------------
// hdr: imp[8] f32 @0, kept[8] i32 @64. etok adjacent so ONE memset covers
// hdr+etok.
#define OFF_ETOK  256u                                 // etok[E][MPAD] i32
#define OFF_TOPI  (OFF_ETOK + 8u*1152u*4u)             // 37120
#define OFF_TOPG  (OFF_TOPI + 4096u*2u*4u)
#define OFF_SLOT  (OFF_TOPG + 4096u*2u*4u)             // slot_map[2*T] i32
#define OFF_XB    (OFF_SLOT + 4096u*2u*4u)             // 135424, 16B aligned
#define XB_BYTES  (4096u*512u*2u)                      // 4,194,304
#define OFF_W1T   (OFF_XB + XB_BYTES)
#define W1T_BYTES (8u*512u*2048u*2u)                   // 16,777,216
#define OFF_W2T   (OFF_W1T + W1T_BYTES)
#define W2T_BYTES (8u*2048u*512u*2u)                   // 16,777,216
#define OFF_H     (OFF_W2T + W2T_BYTES)
#define H_BYTES   (8u*1152u*2048u*2u)                  // 37,748,736
// Ybuf bf16 [E][MPAD][DD] = 9,437,184 B ALIASES W1t (dead after gemm1).
#define OFF_Y     OFF_W1T
// total ~75.6 MB
//
// SESSION LESSONS (r0-r29, MI355X):
//  - split-K fp32 atomics (4x traffic): -37% (r2).
//  - r27 FUSED ATOMIC COMBINE: 2.4x gemm2 REGRESSION (30->98.6us, WRITE
//    17->65 MB, VALUBusy 3%): fp32 atomic scatter epilogues lose even at
//    1:1 traffic — 4B RMW granularity defeats coalescing; VMEM serializes.
//    Gather-combine via slot_map is the right structure on this chip.
//  - LDS XOR swizzle on global-side of global_load_lds: conflicts 7.1M -> 0.
//  - C^T (swapped MFMA operands): packed 8B epilogue stores, +6%.
//  - blockIdx.x=expert XCD affinity: FETCH 46->21 MB.
//  - cooperative fusion via grid.sync: 3x REGRESSION (r6/r7/r10).
//  - r11: gather folded into gemm1 staging. r12 dbuf-drain0: NEUTRAL.
//  - r14 geometry: +7%. r18 counted-vmcnt dbuf: +5% (gemm1 41.2us, BEST 212.5).
//  - r19 MFMA 32x32x16: REFUTED LDS-port theory. Six gemm1 variants all
//    41-46us/~15% MfmaUtil => small-shape plateau; stop tuning gemm1.
//  - r24: prep merge (transpose+router): NEUTRAL (213.9, statistically =
//    r18's 212.5 with one fewer dispatch). Counters: harness poison-fill =
//    2 x 40.9us (256 MiB @ 82% peak) INSIDE the measured window => ~38% of
//    dur_us is uncontrollable; controllable ~130us.
//  - r29 (this round): REVERT to r24 exactly (combine kernel + slot_map).

// ---------------- prep: weight transpose+cast (blocks 0..4095) --------------
// ---------------- + router (blocks 4096..5119) -------------------------------
// Transpose: float4 global reads, LDS 64x65 f32 pad, bf16x8 16B stores.
// Router: logits, softmax, top-2, imp atomics, fused x->bf16 cast.
__global__ __launch_bounds__(256) void prep_kernel(
    const float* __restrict__ fc1, bf16_t* __restrict__ w1t,
    const float* __restrict__ fc2, bf16_t* __restrict__ w2t,
    const float* __restrict__ x, const float* __restrict__ gw,
    float* __restrict__ imp, int* __restrict__ top_i, float* __restrict__ top_g,
    bf16_t* __restrict__ xb) {
  __shared__ float tile[64][65];
  __shared__ float simp[4][E_];
  const int bid = blockIdx.x;
  const int tid = threadIdx.x;

  if (bid < 4096) {                     // ---- transpose part ----
    const int z = bid >> 8;             // 0..15
    const int rem = bid & 255;
    const bool first = (z < 8);
    const int e = first ? z : z - 8;
    const int R = first ? DD : HH;
    const int C = first ? HH : DD;
    const int ct = first ? (rem & 31) : (rem & 7);    // C/64 tiles
    const int rt = first ? (rem >> 5) : (rem >> 3);   // R/64 tiles
    const float* ip = (first ? fc1 : fc2) + (size_t)e * DD * HH;
    bf16_t* op = (first ? w1t : w2t) + (size_t)e * DD * HH;
    const int r0 = rt * 64, c0 = ct * 64;
    const int rr = tid >> 4, c4 = (tid & 15) * 4;     // read: 16 rows/pass, float4
#pragma unroll
    for (int p = 0; p < 4; ++p) {
      const int r = p * 16 + rr;
      const float4 v = *(const float4*)(ip + (size_t)(r0 + r) * C + c0 + c4);
      tile[r][c4 + 0] = v.x; tile[r][c4 + 1] = v.y;
      tile[r][c4 + 2] = v.z; tile[r][c4 + 3] = v.w;
    }
    __syncthreads();
    const int g = tid & 7, ob = tid >> 3;             // write: 8-row groups, 32 cols
#pragma unroll
    for (int p = 0; p < 2; ++p) {
      const int oc = p * 32 + ob;
      bf16_t o8[8];
#pragma unroll
      for (int k = 0; k < 8; ++k) o8[k] = tobf(tile[g * 8 + k][oc]);
      *(bf16x8*)(op + (size_t)(c0 + oc) * R + r0 + g * 8) = *(const bf16x8*)o8;  // 16B store
    }
    return;
  }

  // ---- router part ----
  const int rb = bid - 4096;            // 0..1023
  const int wid = tid >> 6, lane = tid & 63;
  const int t = rb * 4 + wid;

  float p[E_];
#pragma unroll
  for (int e = 0; e < E_; ++e) p[e] = 0.f;
  const float* xr = x + (size_t)t * DD;
  bf16_t* xo = xb + (size_t)t * DD;
#pragma unroll
  for (int it = 0; it < 2; ++it) {
    const int d = it * 256 + lane * 4;
    const float4 xv = *(const float4*)(xr + d);
    bf16_t o4[4] = {tobf(xv.x), tobf(xv.y), tobf(xv.z), tobf(xv.w)};
    *(bf16x4*)(xo + d) = *(const bf16x4*)o4;      // fused bf16 cast (feeds gemm1 A-gather)
#pragma unroll
    for (int e = 0; e < E_; ++e) {
      const float4 gv = *(const float4*)(gw + e * DD + d);
      p[e] += xv.x * gv.x + xv.y * gv.y + xv.z * gv.z + xv.w * gv.w;
    }
  }
#pragma unroll
  for (int off = 32; off > 0; off >>= 1) {
#pragma unroll
    for (int e = 0; e < E_; ++e) p[e] += __shfl_down(p[e], off);
  }

  if (lane == 0) {
    float mx = p[0];
#pragma unroll
    for (int e = 1; e < E_; ++e) mx = fmaxf(mx, p[e]);
    float g[E_]; float s = 0.f;
#pragma unroll
    for (int e = 0; e < E_; ++e) { g[e] = expf(p[e] - mx); s += g[e]; }
    const float inv = 1.f / s;
#pragma unroll
    for (int e = 0; e < E_; ++e) { g[e] *= inv; simp[wid][e] = g[e]; }
    // top-2, ties -> lowest index (matches jax.lax.top_k)
    int i0 = 0;
#pragma unroll
    for (int e = 1; e < E_; ++e) if (g[e] > g[i0]) i0 = e;
    int i1 = (i0 == 0) ? 1 : 0;
#pragma unroll
    for (int e = 0; e < E_; ++e) if (e != i0 && g[e] > g[i1]) i1 = e;
    top_i[t * 2 + 0] = i0;  top_i[t * 2 + 1] = i1;
    top_g[t * 2 + 0] = g[i0]; top_g[t * 2 + 1] = g[i1];
  }
  __syncthreads();
  if (tid < E_) {
    const float s = simp[0][tid] + simp[1][tid] + simp[2][tid] + simp[3][tid];
    atomicAdd(&imp[tid], s);
  }
}

// ---------------- capacity: packed shfl scan + dispatch + slot_map + scalars --
__global__ __launch_bounds__(1024) void capacity_kernel(
    const int* __restrict__ top_i, const float* __restrict__ top_g,
    const float* __restrict__ imp, int* __restrict__ etok,
    int* __restrict__ slot_map, int* __restrict__ kept, float* __restrict__ scal) {
  __shared__ u32 wt[16][4];
  const int tid = threadIdx.x, wave = tid >> 6, lane = tid & 63;

  int eidx[8];
#pragma unroll
  for (int q = 0; q < 8; ++q) {
    const int j = tid * 8 + q;          // slot-major: j = k*T + t
    const int k = j >> 12, t = j & (TT - 1);
    eidx[q] = top_i[t * 2 + k];
  }
  u32 pk[4] = {0u, 0u, 0u, 0u};
#pragma unroll
  for (int q = 0; q < 8; ++q) pk[eidx[q] >> 1] += 1u << ((eidx[q] & 1) * 16);

  u32 v[4] = {pk[0], pk[1], pk[2], pk[3]};   // inclusive wave scan
#pragma unroll
  for (int off = 1; off < 64; off <<= 1) {
#pragma unroll
    for (int p = 0; p < 4; ++p) {
      const u32 n = (u32)__shfl_up((int)v[p], off);
      if (lane >= off) v[p] += n;
    }
  }
  if (lane == 63) {
#pragma unroll
    for (int p = 0; p < 4; ++p) wt[wave][p] = v[p];
  }
  __syncthreads();
  u32 base[4] = {0u, 0u, 0u, 0u}, tot[4] = {0u, 0u, 0u, 0u};
#pragma unroll
  for (int w = 0; w < 16; ++w) {
#pragma unroll
    for (int p = 0; p < 4; ++p) {
      const u32 xv = wt[w][p];
      if (w < wave) base[p] += xv;
      tot[p] += xv;
    }
  }
  int run[E_];
#pragma unroll
  for (int p = 0; p < 4; ++p) {
    const u32 excl = base[p] + v[p] - pk[p];    // exclusive thread prefix
    run[2 * p]     = (int)(excl & 0xFFFFu);
    run[2 * p + 1] = (int)(excl >> 16);
  }
#pragma unroll
  for (int q = 0; q < 8; ++q) {
    const int e = eidx[q];
    const int pos = run[e]++;           // counts ALL earlier same-expert entries
    const int j = tid * 8 + q;
    if (pos < CAP) {
      const int k = j >> 12, t = j & (TT - 1);
      etok[e * MPAD + pos] = t;
      slot_map[j] = (e << 16) | pos;
    } else {
      slot_map[j] = -1;
    }
  }
  if (tid == 0) {
    float tpe[E_];
#pragma unroll
    for (int p = 0; p < 4; ++p) {
      const int t0 = (int)(tot[p] & 0xFFFFu), t1 = (int)(tot[p] >> 16);
      const int k0 = t0 < CAP ? t0 : CAP, k1 = t1 < CAP ? t1 : CAP;
      kept[2 * p] = k0; kept[2 * p + 1] = k1;
      tpe[2 * p] = (float)k0; tpe[2 * p + 1] = (float)k1;
    }
    float ms = 0.f;
#pragma unroll
    for (int e = 0; e < E_; ++e) ms += tpe[e];
    ms *= (1.f / E_);
    float vt = 0.f;
#pragma unroll
    for (int e = 0; e < E_; ++e) { const float d = tpe[e] - ms; vt += d * d; }
    vt *= (1.f / E_);
    const float ll = vt / ((ms + 1e-6f) * (ms + 1e-6f));

    float iv[E_], mi = 0.f;
#pragma unroll
    for (int e = 0; e < E_; ++e) { iv[e] = imp[e]; mi += iv[e]; }
    mi *= (1.f / E_);
    float vi = 0.f;
#pragma unroll
    for (int e = 0; e < E_; ++e) { const float d = iv[e] - mi; vi += d * d; }
    vi *= (1.f / E_);
    const float il = vi / ((mi + 1e-6f) * (mi + 1e-6f));

    scal[0] = 0.5f * (il + ll);   // l_aux
    scal[1] = ll;                 // l_load
  }
}

// ---------------- TN GEMM core: counted-vmcnt dbuf pipeline (r18, proven) ----
// NW waves, tile MR x NC, BK=64 per step, DOUBLE-buffered LDS. Per step:
//   compute(buf s&1) -> s_barrier (all waves done reading) ->
//   stage(s+2 -> buf s&1) -> s_waitcnt vmcnt(L) (waits ONLY for step s+1's
//   loads, issued one full step earlier -> nearly free) -> s_barrier.
// NEVER drains vmcnt to 0 in the loop (m218 mechanism).
// A: GATHER via per-lane etok row lookup on the global source of
// global_load_lds (LDS dest linear). B pre-transposed [col][K].
// acc[j][i] = mfma(bfr[j], af[i], acc) -> C^T tile: lane&15 -> m,
// quad*4+reg -> n -> packed 8B epilogue stores. 16B-chunk XOR swizzle on the
// GLOBAL-side address; read side XORs with l15&7. Conflicts: 0 (proven).
template <int NW, int MR, int NC, int MI, int KLEN, int KSTR, bool GATHER>
__device__ __forceinline__ void gemm_core(
    const bf16_t* __restrict__ Abase, const int* __restrict__ rows,
    const bf16_t* __restrict__ B,
    bf16_t* As, bf16_t* Bs, f32x4 (&acc)[4][MI]) {
  constexpr int NWC = NC / 64;          // wave columns
  constexpr int AIW = MR / (8 * NW);    // A load-instrs per wave per step
  constexpr int BIW = NC / (8 * NW);    // B load-instrs per wave per step
  constexpr int L   = AIW + BIW;        // outstanding loads per staged step
  constexpr int NS  = KLEN / 64;        // K-steps
  constexpr int ABUF = MR * 64;         // elements per A buffer
  constexpr int BBUF = NC * 64;
  static_assert(NS >= 2, "need >=2 K-steps");
  const int tid = threadIdx.x;
  const int wave = tid >> 6, lane = tid & 63;
  const int r8 = lane >> 3;                       // row within 8-row group
  const int kswz = ((lane & 7) ^ r8) * 8;         // swizzled k-offset (elements)
  const bf16_t* ga[AIW];
#pragma unroll
  for (int p = 0; p < AIW; ++p) {
    const int r = (wave * AIW + p) * 8 + r8;
    const int trow = GATHER ? rows[r] : r;        // folded when !GATHER
    ga[p] = Abase + (size_t)trow * KSTR + kswz;
  }
  const bf16_t* gb = B + (size_t)(wave * BIW * 8 + r8) * KSTR + kswz;
  const int mw = (wave / NWC) * (MI * 16), nw = (wave % NWC) * 64;
  const int l15 = lane & 15, quad = lane >> 4;
  const int sw = l15 & 7;                         // read-side swizzle key

  auto stage = [&](int s) {
    const int k0 = s * 64;
    bf16_t* as = As + (s & 1) * ABUF;
    bf16_t* bs = Bs + (s & 1) * BBUF;
#pragma unroll
    for (int p = 0; p < AIW; ++p)
      __builtin_amdgcn_global_load_lds(
          (const __attribute__((address_space(1))) void*)(ga[p] + k0),
          (__attribute__((address_space(3))) void*)(as + ((wave * AIW + p) * 8) * 64),
          16, 0, 0);
#pragma unroll
    for (int p = 0; p < BIW; ++p)
      __builtin_amdgcn_global_load_lds(
          (const __attribute__((address_space(1))) void*)(gb + (size_t)p * 8 * KSTR + k0),
          (__attribute__((address_space(3))) void*)(bs + ((wave * BIW + p) * 8) * 64),
          16, 0, 0);
  };
  auto compute = [&](int s) {
    const bf16_t* as = As + (s & 1) * ABUF;
    const bf16_t* bs = Bs + (s & 1) * BBUF;
#pragma unroll
    for (int kh = 0; kh < 2; ++kh) {
      const int kc = ((kh * 4 + quad) ^ sw) << 3;           // swizzled chunk
      bf16x8 af[MI], bfr[4];
#pragma unroll
      for (int i = 0; i < MI; ++i)
        af[i] = *(const bf16x8*)(as + (mw + i * 16 + l15) * 64 + kc);
#pragma unroll
      for (int j = 0; j < 4; ++j)
        bfr[j] = *(const bf16x8*)(bs + (nw + j * 16 + l15) * 64 + kc);
#pragma unroll
      for (int j = 0; j < 4; ++j)
#pragma unroll
        for (int i = 0; i < MI; ++i)
          acc[j][i] = __builtin_amdgcn_mfma_f32_16x16x32_bf16(bfr[j], af[i], acc[j][i], 0, 0, 0);
    }
  };

  // prologue: two steps in flight
  stage(0);
  stage(1);
  waitcnt_vm<L>();          // own step-0 loads retired (step-1's L still out)
  block_barrier();          // everyone's step-0 loads landed

#pragma unroll
  for (int s = 0; s < NS; ++s) {
    compute(s);
    block_barrier();                    // all waves done READING buf (s&1)
    if (s + 2 < NS) {
      stage(s + 2);                     // refill buf (s&1); 2L outstanding
      waitcnt_vm<L>();                  // oldest L (= step s+1's) retired
      block_barrier();                  // buf ((s+1)&1) ready for all
    } else if (s + 1 < NS) {
      waitcnt_vm<0>();                  // tail: only step s+1's L outstanding
      block_barrier();
    }
  }
}

// ---------------- GEMM1: H = gelu(gather(x) @ W1 + b1), 128x128, 8 waves ----
// blockIdx.x = expert -> XCD (id%8). Early-exit tiles fully past kept[e].
// dbuf LDS 64KB -> 2 blocks/CU, 16 resident waves/CU. L=4 loads/wave/step.
__global__ __launch_bounds__(512, 4) void gemm1_kernel(
    const bf16_t* __restrict__ xb, const int* __restrict__ etok,
    const int* __restrict__ kept, const bf16_t* __restrict__ W1t,
    const float* __restrict__ b1, bf16_t* __restrict__ Hbuf) {
  const int e = blockIdx.x, tileN = blockIdx.y, tileM = blockIdx.z;
  if (tileM * 128 >= kept[e]) return;             // uniform early-exit
  __shared__ __align__(16) bf16_t As[2 * 128 * 64];   // 32 KB
  __shared__ __align__(16) bf16_t Bs[2 * 128 * 64];   // 32 KB
  const bf16_t* B = W1t + ((size_t)e * HH + tileN * 128) * DD;
  f32x4 acc[4][2];
  const f32x4 z = {0.f, 0.f, 0.f, 0.f};
#pragma unroll
  for (int j = 0; j < 4; ++j)
#pragma unroll
    for (int i = 0; i < 2; ++i) acc[j][i] = z;
  gemm_core<8, 128, 128, 2, DD, DD, true>(xb, etok + e * MPAD + tileM * 128, B, As, Bs, acc);

  const int tid = threadIdx.x, wave = tid >> 6, lane = tid & 63;
  const int mw = (wave >> 1) * 32, nw = (wave & 1) * 64;
  const int l15 = lane & 15, quad = lane >> 4;
#pragma unroll
  for (int j = 0; j < 4; ++j) {
    const int n0 = tileN * 128 + nw + j * 16 + quad * 4;   // 4 consecutive n
    const float4 b4 = *(const float4*)(b1 + e * HH + n0);
#pragma unroll
    for (int i = 0; i < 2; ++i) {
      const int m = tileM * 128 + mw + i * 16 + l15;
      bf16x4 h4;
      h4.x = tobf(gelu_f(acc[j][i][0] + b4.x));
      h4.y = tobf(gelu_f(acc[j][i][1] + b4.y));
      h4.z = tobf(gelu_f(acc[j][i][2] + b4.z));
      h4.w = tobf(gelu_f(acc[j][i][3] + b4.w));
      *(bf16x4*)(Hbuf + ((size_t)e * MPAD + m) * HH + n0) = h4;   // 8B store
    }
  }
}

// ---------------- GEMM2: Ybuf = H @ W2 (bf16 out), 64x128, 4 waves ----------
// dbuf LDS 48KB, NS=32 deep pipeline, L=6 loads/wave/step. Hbuf rows in
// [kept, tile-end) are finite garbage; outputs guarded below.
__global__ __launch_bounds__(256, 4) void gemm2_kernel(
    const bf16_t* __restrict__ Hbuf, const bf16_t* __restrict__ W2t,
    const int* __restrict__ kept, bf16_t* __restrict__ Ybuf) {
  const int e = blockIdx.x, tileN = blockIdx.y, tileM = blockIdx.z;
  const int nk = kept[e];
  if (tileM * 64 >= nk) return;                   // uniform early-exit
  __shared__ __align__(16) bf16_t As[2 * 64 * 64];    // 16 KB
  __shared__ __align__(16) bf16_t Bs[2 * 128 * 64];   // 32 KB
  const bf16_t* A = Hbuf + ((size_t)e * MPAD + tileM * 64) * HH;
  const bf16_t* B = W2t + ((size_t)e * DD + tileN * 128) * HH;
  f32x4 acc[4][2];
  const f32x4 z = {0.f, 0.f, 0.f, 0.f};
#pragma unroll
  for (int j = 0; j < 4; ++j)
#pragma unroll
    for (int i = 0; i < 2; ++i) acc[j][i] = z;
  gemm_core<4, 64, 128, 2, HH, HH, false>(A, nullptr, B, As, Bs, acc);

  const int tid = threadIdx.x, wave = tid >> 6, lane = tid & 63;
  const int mw = (wave >> 1) * 32, nw = (wave & 1) * 64;
  const int l15 = lane & 15, quad = lane >> 4;
#pragma unroll
  for (int j = 0; j < 4; ++j) {
    const int n0 = tileN * 128 + nw + j * 16 + quad * 4;   // 4 consecutive n
#pragma unroll
    for (int i = 0; i < 2; ++i) {
      const int m = tileM * 64 + mw + i * 16 + l15;
      if (m < nk) {
        bf16x4 o4;
        o4.x = tobf(acc[j][i][0]);
        o4.y = tobf(acc[j][i][1]);
        o4.z = tobf(acc[j][i][2]);
        o4.w = tobf(acc[j][i][3]);
        *(bf16x4*)(Ybuf + ((size_t)e * MPAD + m) * DD + n0) = o4;  // 8B store
      }
    }
  }
}

// ---------------- combine: out[t] = sum_k w_k * (Ybuf[slot_k] + b2[e_k]) ------
__global__ __launch_bounds__(128) void combine_kernel(
    const bf16_t* __restrict__ Ybuf, const float* __restrict__ b2,
    const int* __restrict__ slot_map, const float* __restrict__ top_g,
    float* __restrict__ out) {
  const int t = blockIdx.x;
  const int c = threadIdx.x * 4;
  float4 acc = {0.f, 0.f, 0.f, 0.f};
#pragma unroll
  for (int k = 0; k < 2; ++k) {
    const int sm = slot_map[k * TT + t];
    if (sm >= 0) {                       // block-uniform branch
      const int e = sm >> 16, pos = sm & 0xFFFF;
      const float w = top_g[t * 2 + k];
      const bf16x4 y4 = *(const bf16x4*)(Ybuf + ((size_t)e * MPAD + pos) * DD + c);
      const float4 bb = *(const float4*)(b2 + e * DD + c);
      acc.x += w * ((float)y4.x + bb.x);
      acc.y += w * ((float)y4.y + bb.y);
      acc.z += w * ((float)y4.z + bb.z);
      acc.w += w * ((float)y4.w + bb.w);
    }
  }
  *(float4*)(out + (size_t)t * DD + c) = acc;
}

// ---------------- launch ----------------
extern "C" void kernel_launch(void* const* d_in, const int* in_sizes, int n_in,
                              void* d_out, int out_size, void* d_ws, size_t ws_size,
                              hipStream_t stream) {
  const float* x      = (const float*)d_in[0];
  const float* gate_w = (const float*)d_in[1];
  const float* fc1_w  = (const float*)d_in[2];
  const float* fc1_b  = (const float*)d_in[3];
  const float* fc2_w  = (const float*)d_in[4];
  const float* fc2_b  = (const float*)d_in[5];
  float* out = (float*)d_out;

  char* ws = (char*)d_ws;
  float*  imp   = (float*)(ws + 0);
  int*    kept  = (int*)(ws + 64);
  int*    etok  = (int*)(ws + OFF_ETOK);
  int*    top_i = (int*)(ws + OFF_TOPI);
  float*  top_g = (float*)(ws + OFF_TOPG);
  int*    slotm = (int*)(ws + OFF_SLOT);
  bf16_t* xb    = (bf16_t*)(ws + OFF_XB);
  bf16_t* W1t   = (bf16_t*)(ws + OFF_W1T);
  bf16_t* W2t   = (bf16_t*)(ws + OFF_W2T);
  bf16_t* Hbuf  = (bf16_t*)(ws + OFF_H);
  bf16_t* Ybuf  = (bf16_t*)(ws + OFF_Y);    // aliases W1t (dead after gemm1)
  float*  scal  = out + (size_t)TT * DD;

  hipMemsetAsync(ws, 0, OFF_TOPI, stream);  // imp atomic base + etok (pad rows -> token 0)

  // transpose (4096 blocks) + router (1024 blocks) merged: independent work,
  // one launch, router hides under transpose's BW time.
  prep_kernel<<<5120, 256, 0, stream>>>(fc1_w, W1t, fc2_w, W2t,
                                        x, gate_w, imp, top_i, top_g, xb);
  capacity_kernel<<<1, 1024, 0, stream>>>(top_i, top_g, imp, etok, slotm, kept, scal);

  // blockIdx.x = expert -> XCD affinity (id % 8 round-robin heuristic)
  gemm1_kernel<<<dim3(E_, HH / 128, MT), 512, 0, stream>>>(xb, etok, kept, W1t, fc1_b, Hbuf);
  gemm2_kernel<<<dim3(E_, DD / 128, MT2), 256, 0, stream>>>(Hbuf, W2t, kept, Ybuf);
  combine_kernel<<<TT, 128, 0, stream>>>(Ybuf, fc2_b, slotm, top_g, out);
}